// Round 3
// baseline (672.460 us; speedup 1.0000x reference)
//
#include <hip/hip_runtime.h>

namespace {

typedef unsigned short ushort_t;
typedef short s16x8 __attribute__((ext_vector_type(8)));
typedef float f32x4 __attribute__((ext_vector_type(4)));

constexpr int B_ = 2, C_ = 64, H_ = 192, W_ = 192;
constexpr int C4 = 256;
constexpr int NPIX = H_ * W_;                       // 36864
constexpr size_t NT = (size_t)B_ * C4 * NPIX;       // 18,874,368
constexpr int PB = NPIX / 32;                       // 1152 pixel-blocks per batch
constexpr float EPSV = 1e-20f;

constexpr int TILE = 32;
constexpr int TLH = TILE + 2;   // 34
constexpr int TDH = TILE + 4;   // 36

__device__ __forceinline__ ushort_t f2bu(float x) {
    union { float f; unsigned u; } v; v.f = x;
    unsigned r = v.u + 0x7fffu + ((v.u >> 16) & 1u);   // RNE to bf16
    return (ushort_t)(r >> 16);
}
__device__ __forceinline__ float bu2f(ushort_t h) {
    union { unsigned u; float f; } v; v.u = ((unsigned)h) << 16;
    return v.f;
}

// ---------------- sums of the two weight tensors ----------------
__global__ __launch_bounds__(256) void k_sums(const float* __restrict__ sw,
                                              const float* __restrict__ cw,
                                              float* __restrict__ sums) {
    __shared__ float red[256];
    int tid = threadIdx.x;
    float a = 0.f;
    for (int i = tid; i < C4 * 9; i += 256) a += sw[i];
    red[tid] = a; __syncthreads();
    for (int s2 = 128; s2 > 0; s2 >>= 1) { if (tid < s2) red[tid] += red[tid + s2]; __syncthreads(); }
    if (tid == 0) sums[0] = red[0];
    __syncthreads();
    float b = 0.f;
    for (int i = tid; i < C4 * C4; i += 256) b += cw[i];
    red[tid] = b; __syncthreads();
    for (int s2 = 128; s2 > 0; s2 >>= 1) { if (tid < s2) red[tid] += red[tid + s2]; __syncthreads(); }
    if (tid == 0) sums[1] = red[0];
}

// ---------------- cw -> split bf16 hi/lo, [O=256][K=256] ----------------
__global__ __launch_bounds__(256) void k_prep(const float* __restrict__ cw,
                                              ushort_t* __restrict__ cwH,
                                              ushort_t* __restrict__ cwL) {
    int i = blockIdx.x * 256 + threadIdx.x;   // grid 256 -> 65536
    float w = cw[i];
    ushort_t h = f2bu(w);
    cwH[i] = h;
    cwL[i] = f2bu(w - bu2f(h));
}

// ---------------- fused stage 1 + stage 2 (depthwise conv) ----------------
// Emits XP/YP: packed split-bf16 of (cs_spatial*s_spatial) and cs_spatial.
// Element (b, pb, g=channel, pix32, j) at ((b*PB+pb)*64 + g)*256 + pix*8 + j,
// j in 0..7 = [hi of k4=0..3 | lo of k4=0..3], c4 = g*4 + k4.
__global__ __launch_bounds__(256) void k_stage12(
    const float* __restrict__ d, const float* __restrict__ cd,
    const float* __restrict__ s, const float* __restrict__ cs,
    const float* __restrict__ w_s_from_d, const float* __restrict__ w_prop,
    const float* __restrict__ sw, const float* __restrict__ sums,
    ushort_t* __restrict__ XP, ushort_t* __restrict__ YP)
{
    __shared__ float ds_[TDH][TDH];
    __shared__ float cds_[TDH][TDH];
    __shared__ float sp_[TLH][TLH];   // cs_prop * s_prop (one sub-channel)
    __shared__ float cp_[TLH][TLH];   // cs_prop
    __shared__ float swl[4][9];

    int tid = threadIdx.x;
    int blk = blockIdx.x;
    constexpr int TX = W_ / TILE, TY = H_ / TILE;   // 6 x 6
    int tx0 = blk % TX; blk /= TX;
    int ty0 = blk % TY; blk /= TY;
    int c = blk % C_;
    int b = blk / C_;
    int h0 = ty0 * TILE, w0 = tx0 * TILE;

    const float* dbc  = d  + (size_t)(b * C_ + c) * NPIX;
    const float* cdbc = cd + (size_t)(b * C_ + c) * NPIX;

    for (int i = tid; i < TDH * TDH; i += 256) {
        int y = i / TDH, x = i % TDH;
        int gh = h0 - 2 + y, gw = w0 - 2 + x;
        bool ok = (gh >= 0 && gh < H_ && gw >= 0 && gw < W_);
        ds_[y][x]  = ok ? dbc[gh * W_ + gw]  : 0.f;
        cds_[y][x] = ok ? cdbc[gh * W_ + gw] : 0.f;
    }
    if (tid < 36) swl[tid / 9][tid % 9] = sw[(c * 4 + tid / 9) * 9 + tid % 9];
    __syncthreads();

    float w0s = w_s_from_d[0];
    float wp  = w_prop[c];
    float inv_wp1 = 1.f / (wp + 1.f);
    float inv_sw  = 1.f / (sums[0] + EPSV);

    s16x8 xp[4], yp[4];   // per-thread packed outputs for 4 pixels

    #pragma unroll
    for (int k = 0; k < 4; ++k) {
        if (k) __syncthreads();   // protect sp_/cp_ from previous conv readers
        // stage 1 for sub-channel k on the halo-1 grid (34x34).
        // Only direction 0 survives the reference's argmax/take_along_axis.
        for (int i = tid; i < TLH * TLH; i += 256) {
            int y = i / TLH, x = i % TLH;
            int gh = h0 - 1 + y, gw = w0 - 1 + x;
            float spv = 0.f, cpv = 0.f;
            if (gh >= 0 && gh < H_ && gw >= 0 && gw < W_) {
                int yy = y + 1, xx = x + 1;
                float mn  = ds_[yy - 1][xx - 1];
                float mx  = ds_[yy + 1][xx + 1];
                float cmn = cds_[yy - 1][xx - 1];
                float cmx = cds_[yy + 1][xx + 1];
                float r = mn / (mx + EPSV);
                r = fminf(fmaxf(r, 0.f), 1.f);
                float sfd = (1.f - w0s) * r + w0s * r * r;
                float cfd = cmn * cmx;
                size_t gidx = ((size_t)((b * C_ + c) * 4 + k)) * NPIX + (size_t)gh * W_ + gw;
                float s_v  = s[gidx];
                float cs_v = cs[gidx];
                float num = wp * cs_v * s_v + cfd * sfd;
                float den = wp * cs_v + cfd;
                float spr = num / (den + EPSV);
                cpv = den * inv_wp1;
                spv = cpv * spr;
            }
            sp_[y][x] = spv;
            cp_[y][x] = cpv;
        }
        __syncthreads();
        // depthwise 3x3 for sub-channel k; accumulate packed bf16 in regs
        #pragma unroll
        for (int p = 0; p < 4; ++p) {
            int i = p * 256 + tid;
            int ty = i >> 5, tx = i & 31;
            float nom = 0.f, den = 0.f;
            #pragma unroll
            for (int dy = 0; dy < 3; ++dy)
                #pragma unroll
                for (int dx = 0; dx < 3; ++dx) {
                    float wgt = swl[k][dy * 3 + dx];
                    nom = fmaf(wgt, sp_[ty + dy][tx + dx], nom);
                    den = fmaf(wgt, cp_[ty + dy][tx + dx], den);
                }
            float csSp = den * inv_sw;
            float sSp  = nom / (den + EPSV);
            float xv = csSp * sSp;
            float yv = csSp;
            ushort_t hx = f2bu(xv);
            ushort_t hy = f2bu(yv);
            xp[p][k]     = (short)hx;
            xp[p][4 + k] = (short)f2bu(xv - bu2f(hx));
            yp[p][k]     = (short)hy;
            yp[p][4 + k] = (short)f2bu(yv - bu2f(hy));
        }
    }

    // fully-coalesced 16B stores
    #pragma unroll
    for (int p = 0; p < 4; ++p) {
        int i = p * 256 + tid;
        int ty = i >> 5, tx = i & 31;
        int pb = (h0 + ty) * (W_ / TILE) + (w0 >> 5);
        size_t base = ((size_t)(b * PB + pb) * 64 + c) * 256 + (size_t)tx * 8;
        *(s16x8*)(XP + base) = xp[p];
        *(s16x8*)(YP + base) = yp[p];
    }
}

// ---------------- stage 3: split-bf16 MFMA GEMM, 2-deep pipelined ----------------
// Block: 256 threads (4 waves), tile = 256 outputs x 32 pixels.
// Wave w: o in [w*64, w*64+64) -> m=4 frags; n=2 pixel frags.
__global__ __launch_bounds__(256) void k_stage3(
    const ushort_t* __restrict__ XP, const ushort_t* __restrict__ YP,
    const ushort_t* __restrict__ cwH, const ushort_t* __restrict__ cwL,
    const float* __restrict__ sums, float* __restrict__ out)
{
    int tid  = threadIdx.x;
    int wave = tid >> 6, lane = tid & 63;
    int l15 = lane & 15, l4 = lane >> 4;
    int pb = blockIdx.x;
    int b  = blockIdx.y;
    int o0 = wave * 64;

    const ushort_t* pAh[4];
    const ushort_t* pAl[4];
    #pragma unroll
    for (int m = 0; m < 4; ++m) {
        pAh[m] = cwH + (size_t)(o0 + m * 16 + l15) * C4;
        pAl[m] = cwL + (size_t)(o0 + m * 16 + l15) * C4;
    }
    size_t xbase = (size_t)(b * PB + pb) * 16384;   // 64 g * 256 ushorts

    f32x4 accn[4][2] = {};
    f32x4 accd[4][2] = {};

    s16x8 rx0[2][2], ry0[2][2], rx1[2][2], ry1[2][2];
    s16x8 ah0[4], al0[4], ah1[4], al1[4];

#define LOADB(ks, rx, ry) do {                                                   \
    _Pragma("unroll")                                                            \
    for (int n = 0; n < 2; ++n) {                                                \
        size_t off = xbase + (size_t)((ks) * 8 + l4 * 2) * 256 + (size_t)(n * 16 + l15) * 8; \
        rx[n][0] = *(const s16x8*)(XP + off);                                    \
        rx[n][1] = *(const s16x8*)(XP + off + 256);                              \
        ry[n][0] = *(const s16x8*)(YP + off);                                    \
        ry[n][1] = *(const s16x8*)(YP + off + 256);                              \
    } } while (0)

#define LOADA(ks, Ah, Al) do {                                                   \
    _Pragma("unroll")                                                            \
    for (int m = 0; m < 4; ++m) {                                                \
        Ah[m] = *(const s16x8*)(pAh[m] + (ks) * 32 + l4 * 8);                    \
        Al[m] = *(const s16x8*)(pAl[m] + (ks) * 32 + l4 * 8);                    \
    } } while (0)

#define COMPUTE(rx, ry, Ah, Al) do {                                             \
    _Pragma("unroll")                                                            \
    for (int n = 0; n < 2; ++n) {                                                \
        s16x8 bxh = __builtin_shufflevector(rx[n][0], rx[n][1], 0,1,2,3, 8,9,10,11);  \
        s16x8 bxl = __builtin_shufflevector(rx[n][0], rx[n][1], 4,5,6,7, 12,13,14,15);\
        s16x8 byh = __builtin_shufflevector(ry[n][0], ry[n][1], 0,1,2,3, 8,9,10,11);  \
        s16x8 byl = __builtin_shufflevector(ry[n][0], ry[n][1], 4,5,6,7, 12,13,14,15);\
        _Pragma("unroll")                                                        \
        for (int m = 0; m < 4; ++m) {                                            \
            accn[m][n] = __builtin_amdgcn_mfma_f32_16x16x32_bf16(Ah[m], bxh, accn[m][n], 0, 0, 0); \
            accn[m][n] = __builtin_amdgcn_mfma_f32_16x16x32_bf16(Ah[m], bxl, accn[m][n], 0, 0, 0); \
            accn[m][n] = __builtin_amdgcn_mfma_f32_16x16x32_bf16(Al[m], bxh, accn[m][n], 0, 0, 0); \
            accd[m][n] = __builtin_amdgcn_mfma_f32_16x16x32_bf16(Ah[m], byh, accd[m][n], 0, 0, 0); \
            accd[m][n] = __builtin_amdgcn_mfma_f32_16x16x32_bf16(Ah[m], byl, accd[m][n], 0, 0, 0); \
            accd[m][n] = __builtin_amdgcn_mfma_f32_16x16x32_bf16(Al[m], byh, accd[m][n], 0, 0, 0); \
        } } } while (0)

    LOADB(0, rx0, ry0); LOADA(0, ah0, al0);
    LOADB(1, rx1, ry1); LOADA(1, ah1, al1);
    COMPUTE(rx0, ry0, ah0, al0);
    LOADB(2, rx0, ry0); LOADA(2, ah0, al0);
    COMPUTE(rx1, ry1, ah1, al1);
    LOADB(3, rx1, ry1); LOADA(3, ah1, al1);
    COMPUTE(rx0, ry0, ah0, al0);
    LOADB(4, rx0, ry0); LOADA(4, ah0, al0);
    COMPUTE(rx1, ry1, ah1, al1);
    LOADB(5, rx1, ry1); LOADA(5, ah1, al1);
    COMPUTE(rx0, ry0, ah0, al0);
    LOADB(6, rx0, ry0); LOADA(6, ah0, al0);
    COMPUTE(rx1, ry1, ah1, al1);
    LOADB(7, rx1, ry1); LOADA(7, ah1, al1);
    COMPUTE(rx0, ry0, ah0, al0);
    COMPUTE(rx1, ry1, ah1, al1);

#undef LOADB
#undef LOADA
#undef COMPUTE

    float inv_scw = 1.f / (sums[1] + EPSV);
    #pragma unroll
    for (int m = 0; m < 4; ++m)
        #pragma unroll
        for (int n = 0; n < 2; ++n)
            #pragma unroll
            for (int r = 0; r < 4; ++r) {
                int o   = o0 + m * 16 + l4 * 4 + r;
                int pix = pb * 32 + n * 16 + l15;
                size_t oidx = ((size_t)(b * C4 + o)) * NPIX + pix;
                float nv = accn[m][n][r], dv = accd[m][n][r];
                out[oidx]      = nv / (dv + EPSV);
                out[NT + oidx] = dv * inv_scw;
            }
}

} // namespace

extern "C" void kernel_launch(void* const* d_in, const int* in_sizes, int n_in,
                              void* d_out, int out_size, void* d_ws, size_t ws_size,
                              hipStream_t stream) {
    const float* d    = (const float*)d_in[0];
    const float* cd   = (const float*)d_in[1];
    const float* s    = (const float*)d_in[2];
    const float* cs   = (const float*)d_in[3];
    const float* w_s  = (const float*)d_in[4];
    const float* wprp = (const float*)d_in[5];
    const float* cw   = (const float*)d_in[6];
    const float* sw   = (const float*)d_in[7];
    float* out = (float*)d_out;

    ushort_t* XP  = (ushort_t*)d_ws;
    ushort_t* YP  = XP + 2 * NT;
    ushort_t* cwH = YP + 2 * NT;
    ushort_t* cwL = cwH + C4 * C4;
    float* sums   = (float*)(cwL + C4 * C4);

    k_sums<<<1, 256, 0, stream>>>(sw, cw, sums);
    k_prep<<<C4, 256, 0, stream>>>(cw, cwH, cwL);
    k_stage12<<<dim3(B_ * C_ * (H_ / TILE) * (W_ / TILE)), 256, 0, stream>>>(
        d, cd, s, cs, w_s, wprp, sw, sums, XP, YP);
    k_stage3<<<dim3(PB, B_), 256, 0, stream>>>(XP, YP, cwH, cwL, sums, out);
}

// Round 4
// 341.178 us; speedup vs baseline: 1.9710x; 1.9710x over previous
//
#include <hip/hip_runtime.h>

namespace {

typedef unsigned short ushort_t;
typedef short s16x8 __attribute__((ext_vector_type(8)));
typedef float f32x4 __attribute__((ext_vector_type(4)));

constexpr int B_ = 2, C_ = 64, H_ = 192, W_ = 192;
constexpr int C4 = 256;
constexpr int NPIX = H_ * W_;                       // 36864
constexpr size_t NT = (size_t)B_ * C4 * NPIX;       // 18,874,368
constexpr int PB = NPIX / 32;                       // 1152 pixel-blocks per batch
constexpr float EPSV = 1e-20f;

constexpr int TILE = 32;
constexpr int TLH = TILE + 2;   // 34
constexpr int CHUNK = 2048;     // ushorts per tensor per k-chunk (4 KB)

__device__ __forceinline__ ushort_t f2bu(float x) {
    union { float f; unsigned u; } v; v.f = x;
    unsigned r = v.u + 0x7fffu + ((v.u >> 16) & 1u);   // RNE to bf16
    return (ushort_t)(r >> 16);
}
__device__ __forceinline__ float bu2f(ushort_t h) {
    union { unsigned u; float f; } v; v.u = ((unsigned)h) << 16;
    return v.f;
}

__device__ __forceinline__ void async_ld16(const ushort_t* g, ushort_t* l) {
    __builtin_amdgcn_global_load_lds(
        (const __attribute__((address_space(1))) unsigned int*)g,
        (__attribute__((address_space(3))) unsigned int*)l, 16, 0, 0);
}

// ---------------- sums of the two weight tensors ----------------
__global__ __launch_bounds__(256) void k_sums(const float* __restrict__ sw,
                                              const float* __restrict__ cw,
                                              float* __restrict__ sums) {
    __shared__ float red[256];
    int tid = threadIdx.x;
    float a = 0.f;
    for (int i = tid; i < C4 * 9; i += 256) a += sw[i];
    red[tid] = a; __syncthreads();
    for (int s2 = 128; s2 > 0; s2 >>= 1) { if (tid < s2) red[tid] += red[tid + s2]; __syncthreads(); }
    if (tid == 0) sums[0] = red[0];
    __syncthreads();
    float b = 0.f;
    for (int i = tid; i < C4 * C4; i += 256) b += cw[i];
    red[tid] = b; __syncthreads();
    for (int s2 = 128; s2 > 0; s2 >>= 1) { if (tid < s2) red[tid] += red[tid + s2]; __syncthreads(); }
    if (tid == 0) sums[1] = red[0];
}

// ---------------- cw -> split bf16 hi/lo, [O=256][K=256] ----------------
__global__ __launch_bounds__(256) void k_prep(const float* __restrict__ cw,
                                              ushort_t* __restrict__ cwH,
                                              ushort_t* __restrict__ cwL) {
    int i = blockIdx.x * 256 + threadIdx.x;   // grid 256 -> 65536
    float w = cw[i];
    ushort_t h = f2bu(w);
    cwH[i] = h;
    cwL[i] = f2bu(w - bu2f(h));
}

// ---------------- fused stage 1 + stage 2 (depthwise conv) ----------------
// Divisions cancel: U = cs_prop*s_prop = (wp*cs*s + cfd*sfd)/(wp+1) and
// X = cs_spatial*s_spatial = conv(U)/sum_sw (up to den/(den+1e-20) == 1).
// Emits XP/YP packed split-bf16: element (b, pb, g, pix32, j) at
// ((b*PB+pb)*64 + g)*256 + pix*8 + j ; j = [hi k4 0..3 | lo k4 0..3].
__global__ __launch_bounds__(256) void k_stage12(
    const float* __restrict__ d, const float* __restrict__ cd,
    const float* __restrict__ s, const float* __restrict__ cs,
    const float* __restrict__ w_s_from_d, const float* __restrict__ w_prop,
    const float* __restrict__ sw, const float* __restrict__ sums,
    ushort_t* __restrict__ XP, ushort_t* __restrict__ YP)
{
    __shared__ float u_[4][TLH][TLH + 1];   // 19,040 B
    __shared__ float v_[4][TLH][TLH + 1];   // 19,040 B
    __shared__ float swl[4][9];

    int tid = threadIdx.x;
    int blk = blockIdx.x;
    constexpr int TX = W_ / TILE, TY = H_ / TILE;   // 6 x 6
    int tx0 = blk % TX; blk /= TX;
    int ty0 = blk % TY; blk /= TY;
    int c = blk % C_;
    int b = blk / C_;
    int h0 = ty0 * TILE, w0 = tx0 * TILE;

    const float* dbc  = d  + (size_t)(b * C_ + c) * NPIX;
    const float* cdbc = cd + (size_t)(b * C_ + c) * NPIX;

    if (tid < 36) swl[tid / 9][tid % 9] = sw[(c * 4 + tid / 9) * 9 + tid % 9];

    float w0s = w_s_from_d[0];
    float wp  = w_prop[c];
    float inv_wp1 = 1.f / (wp + 1.f);
    float inv_sw  = 1.f / (sums[0] + EPSV);
    float b1 = wp * inv_wp1;

    // stage 1 on the halo-1 grid (34x34); only direction 0 survives the
    // reference's argmax over identical stacked copies.
    for (int i = tid; i < TLH * TLH; i += 256) {
        int y = i / TLH, x = i - y * TLH;
        int gh = h0 - 1 + y, gw = w0 - 1 + x;
        if ((unsigned)gh < (unsigned)H_ && (unsigned)gw < (unsigned)W_) {
            float mn = 0.f, cmn = 0.f, mx = 0.f, cmx = 0.f;
            if (gh >= 1 && gw >= 1) {
                size_t q = (size_t)(gh - 1) * W_ + (gw - 1);
                mn = dbc[q]; cmn = cdbc[q];
            }
            if (gh < H_ - 1 && gw < W_ - 1) {
                size_t q = (size_t)(gh + 1) * W_ + (gw + 1);
                mx = dbc[q]; cmx = cdbc[q];
            }
            float r = __fdividef(mn, mx + EPSV);
            r = fminf(fmaxf(r, 0.f), 1.f);
            float sfd = r * fmaf(w0s, r, 1.f - w0s);
            float cfd = cmn * cmx;
            float a1 = cfd * sfd * inv_wp1;
            float c1 = cfd * inv_wp1;
            size_t gbase = (size_t)((b * C_ + c) * 4) * NPIX + (size_t)gh * W_ + gw;
            #pragma unroll
            for (int k = 0; k < 4; ++k) {
                float s_v  = s[gbase + (size_t)k * NPIX];
                float cs_v = cs[gbase + (size_t)k * NPIX];
                float t = b1 * cs_v;
                u_[k][y][x] = fmaf(t, s_v, a1);   // cs_prop * s_prop
                v_[k][y][x] = t + c1;             // cs_prop
            }
        } else {
            #pragma unroll
            for (int k = 0; k < 4; ++k) { u_[k][y][x] = 0.f; v_[k][y][x] = 0.f; }
        }
    }
    __syncthreads();

    // depthwise 3x3 (linear) + scale + split-bf16 pack + coalesced 16B stores
    int pbw = w0 >> 5;
    #pragma unroll
    for (int p = 0; p < 4; ++p) {
        int i = p * 256 + tid;
        int ty = i >> 5, tx = i & 31;
        s16x8 xv8, yv8;
        #pragma unroll
        for (int k = 0; k < 4; ++k) {
            float nom = 0.f, den = 0.f;
            #pragma unroll
            for (int dy = 0; dy < 3; ++dy)
                #pragma unroll
                for (int dx = 0; dx < 3; ++dx) {
                    float wgt = swl[k][dy * 3 + dx];
                    nom = fmaf(wgt, u_[k][ty + dy][tx + dx], nom);
                    den = fmaf(wgt, v_[k][ty + dy][tx + dx], den);
                }
            float xv = nom * inv_sw;
            float yv = den * inv_sw;
            ushort_t hx = f2bu(xv);
            ushort_t hy = f2bu(yv);
            xv8[k]     = (short)hx;
            xv8[4 + k] = (short)f2bu(xv - bu2f(hx));
            yv8[k]     = (short)hy;
            yv8[4 + k] = (short)f2bu(yv - bu2f(hy));
        }
        int pb = (h0 + ty) * (W_ / TILE) + pbw;
        size_t base = ((size_t)(b * PB + pb) * 64 + c) * 256 + (size_t)tx * 8;
        *(s16x8*)(XP + base) = xv8;
        *(s16x8*)(YP + base) = yv8;
    }
}

// ---------------- stage 3: split-bf16 MFMA GEMM, async-LDS pipelined ----------------
// 512 threads (8 waves). Block tile: 256 o x 32 pix. Wave w: o in [w*32,(w+1)*32).
// B-stream (XP/YP k-chunks, 4 KB each) staged via global_load_lds into a
// 4-deep LDS ring; counted vmcnt keeps 3 chunks in flight (T3/T4).
__global__ __launch_bounds__(512) void k_stage3(
    const ushort_t* __restrict__ XP, const ushort_t* __restrict__ YP,
    const ushort_t* __restrict__ cwH, const ushort_t* __restrict__ cwL,
    const float* __restrict__ sums, float* __restrict__ out)
{
    __shared__ ushort_t stg[4 * 2 * CHUNK];   // 32 KiB: 4 bufs x [XP 4KB | YP 4KB]

    int tid  = threadIdx.x;
    int wave = tid >> 6, lane = tid & 63;
    int l15 = lane & 15, l4 = lane >> 4;
    int pb = blockIdx.x;
    int b  = blockIdx.y;
    int o0 = wave * 32;

    size_t xbase = (size_t)(b * PB + pb) * 16384;   // ushorts: 64 g * 256
    const ushort_t* gsrc = ((wave & 4) ? YP : XP) + xbase
                         + (size_t)(wave & 3) * 512 + (size_t)lane * 8;
    ushort_t* lbase = stg + ((wave & 4) ? CHUNK : 0) + (wave & 3) * 512;

    f32x4 accn[2][2] = {};
    f32x4 accd[2][2] = {};
    s16x8 rx[2][2], ry[2][2];
    s16x8 rAh[2][2], rAl[2][2];

#define MFMA __builtin_amdgcn_mfma_f32_16x16x32_bf16

#define STAGE(BI, KS) async_ld16(gsrc + (size_t)(KS) * 2048, lbase + (BI) * (2 * CHUNK))

#define LOADA(AB, KS) do {                                                        \
    _Pragma("unroll")                                                             \
    for (int m = 0; m < 2; ++m) {                                                 \
        size_t ro = (size_t)(o0 + m * 16 + l15) * C4 + (KS) * 32 + l4 * 8;        \
        rAh[AB][m] = *(const s16x8*)(cwH + ro);                                   \
        rAl[AB][m] = *(const s16x8*)(cwL + ro);                                   \
    } } while (0)

#define LOADB(BI) do {                                                            \
    const ushort_t* bp = stg + (BI) * (2 * CHUNK);                                \
    _Pragma("unroll")                                                             \
    for (int n = 0; n < 2; ++n)                                                   \
        _Pragma("unroll")                                                         \
        for (int gg = 0; gg < 2; ++gg) {                                          \
            int o_ = (l4 * 2 + gg) * 256 + (n * 16 + l15) * 8;                    \
            rx[n][gg] = *(const s16x8*)(bp + o_);                                 \
            ry[n][gg] = *(const s16x8*)(bp + CHUNK + o_);                         \
        } } while (0)

#define COMPUTE(AB) do {                                                          \
    _Pragma("unroll")                                                             \
    for (int n = 0; n < 2; ++n) {                                                 \
        s16x8 bxh = __builtin_shufflevector(rx[n][0], rx[n][1], 0,1,2,3, 8,9,10,11);   \
        s16x8 bxl = __builtin_shufflevector(rx[n][0], rx[n][1], 4,5,6,7, 12,13,14,15); \
        s16x8 byh = __builtin_shufflevector(ry[n][0], ry[n][1], 0,1,2,3, 8,9,10,11);   \
        s16x8 byl = __builtin_shufflevector(ry[n][0], ry[n][1], 4,5,6,7, 12,13,14,15); \
        _Pragma("unroll")                                                         \
        for (int m = 0; m < 2; ++m) {                                             \
            accn[m][n] = MFMA(rAh[AB][m], bxh, accn[m][n], 0, 0, 0);              \
            accn[m][n] = MFMA(rAh[AB][m], bxl, accn[m][n], 0, 0, 0);              \
            accn[m][n] = MFMA(rAl[AB][m], bxh, accn[m][n], 0, 0, 0);              \
            accd[m][n] = MFMA(rAh[AB][m], byh, accd[m][n], 0, 0, 0);              \
            accd[m][n] = MFMA(rAh[AB][m], byl, accd[m][n], 0, 0, 0);              \
            accd[m][n] = MFMA(rAl[AB][m], byh, accd[m][n], 0, 0, 0);              \
        } } } while (0)

// One pipeline iteration. NSTR = exact count of VMEM ops issued after chunk K
// at this point (in-order retirement makes the counted wait exact).
#define ITER(K, NSTR, DO_A, DO_S)                                                 \
    asm volatile("s_waitcnt vmcnt(" NSTR ")" ::: "memory");                       \
    asm volatile("s_waitcnt lgkmcnt(0)" ::: "memory");                            \
    __builtin_amdgcn_s_barrier();                                                 \
    __builtin_amdgcn_sched_barrier(0);                                            \
    DO_A;                                                                         \
    __builtin_amdgcn_sched_barrier(0);                                            \
    DO_S;                                                                         \
    __builtin_amdgcn_sched_barrier(0);                                            \
    LOADB((K) & 3);                                                               \
    COMPUTE((K) & 1);

    // prologue: 3 chunks in flight + A0
    STAGE(0, 0); STAGE(1, 1); STAGE(2, 2);
    __builtin_amdgcn_sched_barrier(0);
    LOADA(0, 0);
    __builtin_amdgcn_sched_barrier(0);

    ITER(0, "6",  LOADA(1, 1), STAGE(3, 3));
    ITER(1, "10", LOADA(0, 2), STAGE(0, 4));
    ITER(2, "14", LOADA(1, 3), STAGE(1, 5));
    ITER(3, "10", LOADA(0, 4), STAGE(2, 6));
    ITER(4, "10", LOADA(1, 5), STAGE(3, 7));
    ITER(5, "10", LOADA(0, 6), (void)0);
    ITER(6, "9",  LOADA(1, 7), (void)0);
    ITER(7, "8",  (void)0,     (void)0);

#undef ITER
#undef COMPUTE
#undef LOADB
#undef LOADA
#undef STAGE
#undef MFMA

    float inv_scw = 1.f / (sums[1] + EPSV);
    #pragma unroll
    for (int m = 0; m < 2; ++m)
        #pragma unroll
        for (int n = 0; n < 2; ++n)
            #pragma unroll
            for (int r = 0; r < 4; ++r) {
                int o   = o0 + m * 16 + l4 * 4 + r;
                int pix = pb * 32 + n * 16 + l15;
                size_t oidx = ((size_t)(b * C4 + o)) * NPIX + pix;
                float nv = accn[m][n][r], dv = accd[m][n][r];
                out[oidx]      = nv / (dv + EPSV);
                out[NT + oidx] = dv * inv_scw;
            }
}

} // namespace

extern "C" void kernel_launch(void* const* d_in, const int* in_sizes, int n_in,
                              void* d_out, int out_size, void* d_ws, size_t ws_size,
                              hipStream_t stream) {
    const float* d    = (const float*)d_in[0];
    const float* cd   = (const float*)d_in[1];
    const float* s    = (const float*)d_in[2];
    const float* cs   = (const float*)d_in[3];
    const float* w_s  = (const float*)d_in[4];
    const float* wprp = (const float*)d_in[5];
    const float* cw   = (const float*)d_in[6];
    const float* sw   = (const float*)d_in[7];
    float* out = (float*)d_out;

    ushort_t* XP  = (ushort_t*)d_ws;
    ushort_t* YP  = XP + 2 * NT;
    ushort_t* cwH = YP + 2 * NT;
    ushort_t* cwL = cwH + C4 * C4;
    float* sums   = (float*)(cwL + C4 * C4);

    k_sums<<<1, 256, 0, stream>>>(sw, cw, sums);
    k_prep<<<C4, 256, 0, stream>>>(cw, cwH, cwL);
    k_stage12<<<dim3(B_ * C_ * (H_ / TILE) * (W_ / TILE)), 256, 0, stream>>>(
        d, cd, s, cs, w_s, wprp, sw, sums, XP, YP);
    k_stage3<<<dim3(PB, B_), 512, 0, stream>>>(XP, YP, cwH, cwL, sums, out);
}

// Round 5
// 336.516 us; speedup vs baseline: 1.9983x; 1.0139x over previous
//
#include <hip/hip_runtime.h>

namespace {

typedef unsigned short ushort_t;
typedef short s16x8 __attribute__((ext_vector_type(8)));
typedef float f32x4 __attribute__((ext_vector_type(4)));

constexpr int B_ = 2, C_ = 64, H_ = 192, W_ = 192;
constexpr int C4 = 256;
constexpr int NPIX = H_ * W_;                       // 36864
constexpr size_t NT = (size_t)B_ * C4 * NPIX;       // 18,874,368
constexpr int PB = NPIX / 32;                       // 1152 pixel-blocks per batch
constexpr float EPSV = 1e-20f;

constexpr int TILE = 32;
constexpr int TLH = TILE + 2;   // 34
constexpr int CHUNK = 2048;     // ushorts per tensor per k-chunk (4 KB)

__device__ __forceinline__ ushort_t f2bu(float x) {
    union { float f; unsigned u; } v; v.f = x;
    unsigned r = v.u + 0x7fffu + ((v.u >> 16) & 1u);   // RNE to bf16
    return (ushort_t)(r >> 16);
}
__device__ __forceinline__ float bu2f(ushort_t h) {
    union { unsigned u; float f; } v; v.u = ((unsigned)h) << 16;
    return v.f;
}

__device__ __forceinline__ void async_ld16(const ushort_t* g, ushort_t* l) {
    __builtin_amdgcn_global_load_lds(
        (const __attribute__((address_space(1))) unsigned int*)g,
        (__attribute__((address_space(3))) unsigned int*)l, 16, 0, 0);
}

// ---------------- sums of the two weight tensors ----------------
__global__ __launch_bounds__(256) void k_sums(const float* __restrict__ sw,
                                              const float* __restrict__ cw,
                                              float* __restrict__ sums) {
    __shared__ float red[256];
    int tid = threadIdx.x;
    float a = 0.f;
    for (int i = tid; i < C4 * 9; i += 256) a += sw[i];
    red[tid] = a; __syncthreads();
    for (int s2 = 128; s2 > 0; s2 >>= 1) { if (tid < s2) red[tid] += red[tid + s2]; __syncthreads(); }
    if (tid == 0) sums[0] = red[0];
    __syncthreads();
    float b = 0.f;
    for (int i = tid; i < C4 * C4; i += 256) b += cw[i];
    red[tid] = b; __syncthreads();
    for (int s2 = 128; s2 > 0; s2 >>= 1) { if (tid < s2) red[tid] += red[tid + s2]; __syncthreads(); }
    if (tid == 0) sums[1] = red[0];
}

// ---------------- cw -> split bf16 hi/lo, [O=256][K=256] ----------------
__global__ __launch_bounds__(256) void k_prep(const float* __restrict__ cw,
                                              ushort_t* __restrict__ cwH,
                                              ushort_t* __restrict__ cwL) {
    int i = blockIdx.x * 256 + threadIdx.x;   // grid 256 -> 65536
    float w = cw[i];
    ushort_t h = f2bu(w);
    cwH[i] = h;
    cwL[i] = f2bu(w - bu2f(h));
}

// ---------------- fused stage 1 + stage 2 (depthwise conv) ----------------
// Divisions cancel: U = cs_prop*s_prop = (wp*cs*s + cfd*sfd)/(wp+1) and
// X = cs_spatial*s_spatial = conv(U)/sum_sw (up to den/(den+1e-20) == 1).
// Emits XP/YP packed split-bf16: element (b, pb, g, pix32, j) at
// ((b*PB+pb)*64 + g)*256 + pix*8 + j ; j = [hi k4 0..3 | lo k4 0..3].
__global__ __launch_bounds__(256) void k_stage12(
    const float* __restrict__ d, const float* __restrict__ cd,
    const float* __restrict__ s, const float* __restrict__ cs,
    const float* __restrict__ w_s_from_d, const float* __restrict__ w_prop,
    const float* __restrict__ sw, const float* __restrict__ sums,
    ushort_t* __restrict__ XP, ushort_t* __restrict__ YP)
{
    __shared__ float u_[4][TLH][TLH + 1];   // 19,040 B
    __shared__ float v_[4][TLH][TLH + 1];   // 19,040 B
    __shared__ float swl[4][9];

    int tid = threadIdx.x;
    int blk = blockIdx.x;
    constexpr int TX = W_ / TILE, TY = H_ / TILE;   // 6 x 6
    int tx0 = blk % TX; blk /= TX;
    int ty0 = blk % TY; blk /= TY;
    int c = blk % C_;
    int b = blk / C_;
    int h0 = ty0 * TILE, w0 = tx0 * TILE;

    const float* dbc  = d  + (size_t)(b * C_ + c) * NPIX;
    const float* cdbc = cd + (size_t)(b * C_ + c) * NPIX;

    if (tid < 36) swl[tid / 9][tid % 9] = sw[(c * 4 + tid / 9) * 9 + tid % 9];

    float w0s = w_s_from_d[0];
    float wp  = w_prop[c];
    float inv_wp1 = 1.f / (wp + 1.f);
    float inv_sw  = 1.f / (sums[0] + EPSV);
    float b1 = wp * inv_wp1;

    // stage 1 on the halo-1 grid (34x34); only direction 0 survives the
    // reference's argmax over identical stacked copies.
    for (int i = tid; i < TLH * TLH; i += 256) {
        int y = i / TLH, x = i - y * TLH;
        int gh = h0 - 1 + y, gw = w0 - 1 + x;
        if ((unsigned)gh < (unsigned)H_ && (unsigned)gw < (unsigned)W_) {
            float mn = 0.f, cmn = 0.f, mx = 0.f, cmx = 0.f;
            if (gh >= 1 && gw >= 1) {
                size_t q = (size_t)(gh - 1) * W_ + (gw - 1);
                mn = dbc[q]; cmn = cdbc[q];
            }
            if (gh < H_ - 1 && gw < W_ - 1) {
                size_t q = (size_t)(gh + 1) * W_ + (gw + 1);
                mx = dbc[q]; cmx = cdbc[q];
            }
            float r = __fdividef(mn, mx + EPSV);
            r = fminf(fmaxf(r, 0.f), 1.f);
            float sfd = r * fmaf(w0s, r, 1.f - w0s);
            float cfd = cmn * cmx;
            float a1 = cfd * sfd * inv_wp1;
            float c1 = cfd * inv_wp1;
            size_t gbase = (size_t)((b * C_ + c) * 4) * NPIX + (size_t)gh * W_ + gw;
            #pragma unroll
            for (int k = 0; k < 4; ++k) {
                float s_v  = s[gbase + (size_t)k * NPIX];
                float cs_v = cs[gbase + (size_t)k * NPIX];
                float t = b1 * cs_v;
                u_[k][y][x] = fmaf(t, s_v, a1);   // cs_prop * s_prop
                v_[k][y][x] = t + c1;             // cs_prop
            }
        } else {
            #pragma unroll
            for (int k = 0; k < 4; ++k) { u_[k][y][x] = 0.f; v_[k][y][x] = 0.f; }
        }
    }
    __syncthreads();

    // depthwise 3x3 (linear) + scale + split-bf16 pack + coalesced 16B stores
    int pbw = w0 >> 5;
    #pragma unroll
    for (int p = 0; p < 4; ++p) {
        int i = p * 256 + tid;
        int ty = i >> 5, tx = i & 31;
        s16x8 xv8, yv8;
        #pragma unroll
        for (int k = 0; k < 4; ++k) {
            float nom = 0.f, den = 0.f;
            #pragma unroll
            for (int dy = 0; dy < 3; ++dy)
                #pragma unroll
                for (int dx = 0; dx < 3; ++dx) {
                    float wgt = swl[k][dy * 3 + dx];
                    nom = fmaf(wgt, u_[k][ty + dy][tx + dx], nom);
                    den = fmaf(wgt, v_[k][ty + dy][tx + dx], den);
                }
            float xv = nom * inv_sw;
            float yv = den * inv_sw;
            ushort_t hx = f2bu(xv);
            ushort_t hy = f2bu(yv);
            xv8[k]     = (short)hx;
            xv8[4 + k] = (short)f2bu(xv - bu2f(hx));
            yv8[k]     = (short)hy;
            yv8[4 + k] = (short)f2bu(yv - bu2f(hy));
        }
        int pb = (h0 + ty) * (W_ / TILE) + pbw;
        size_t base = ((size_t)(b * PB + pb) * 64 + c) * 256 + (size_t)tx * 8;
        *(s16x8*)(XP + base) = xv8;
        *(s16x8*)(YP + base) = yv8;
    }
}

// ---------------- stage 3: split-bf16 MFMA GEMM, monolithic LDS stage ----------------
// 512 threads (8 waves). Block tile: 256 o x 32 pix. Wave w: o in [w*32,(w+1)*32).
// Whole B-panel (X+Y = 64 KB) staged up-front via global_load_lds; TWO barriers
// total: phase A (chunks 0-3) overlaps the in-flight staging of chunks 4-7.
__global__ __launch_bounds__(512, 4) void k_stage3(
    const ushort_t* __restrict__ XP, const ushort_t* __restrict__ YP,
    const ushort_t* __restrict__ cwH, const ushort_t* __restrict__ cwL,
    const float* __restrict__ sums, float* __restrict__ out)
{
    __shared__ ushort_t stg[8 * 2 * CHUNK];   // 64 KiB: 8 chunks x [X 4KB | Y 4KB]

    int tid  = threadIdx.x;
    int wave = tid >> 6, lane = tid & 63;
    int l15 = lane & 15, l4 = lane >> 4;
    int pb = blockIdx.x;
    int b  = blockIdx.y;
    int o0 = wave * 32;

    size_t xbase = (size_t)(b * PB + pb) * 16384;   // ushorts: 64 g * 256
    const ushort_t* gsrc = ((wave & 4) ? YP : XP) + xbase
                         + (size_t)(wave & 3) * 512 + (size_t)lane * 8;
    ushort_t* lbase = stg + ((wave & 4) ? CHUNK : 0) + (wave & 3) * 512;

    f32x4 accn[2][2] = {};
    f32x4 accd[2][2] = {};
    s16x8 rx[2][2], ry[2][2];
    s16x8 rAh[2][2], rAl[2][2];

#define MFMA __builtin_amdgcn_mfma_f32_16x16x32_bf16

#define STAGE(KS) async_ld16(gsrc + (size_t)(KS) * 2048, lbase + (KS) * (2 * CHUNK))

#define LOADA(AB, KS) do {                                                        \
    _Pragma("unroll")                                                             \
    for (int m = 0; m < 2; ++m) {                                                 \
        size_t ro = (size_t)(o0 + m * 16 + l15) * C4 + (KS) * 32 + l4 * 8;        \
        rAh[AB][m] = *(const s16x8*)(cwH + ro);                                   \
        rAl[AB][m] = *(const s16x8*)(cwL + ro);                                   \
    } } while (0)

#define LOADB(KS) do {                                                            \
    const ushort_t* bp = stg + (KS) * (2 * CHUNK);                                \
    _Pragma("unroll")                                                             \
    for (int n = 0; n < 2; ++n)                                                   \
        _Pragma("unroll")                                                         \
        for (int gg = 0; gg < 2; ++gg) {                                          \
            int o_ = (l4 * 2 + gg) * 256 + (n * 16 + l15) * 8;                    \
            rx[n][gg] = *(const s16x8*)(bp + o_);                                 \
            ry[n][gg] = *(const s16x8*)(bp + CHUNK + o_);                         \
        } } while (0)

#define COMPUTE(AB) do {                                                          \
    _Pragma("unroll")                                                             \
    for (int n = 0; n < 2; ++n) {                                                 \
        s16x8 bxh = __builtin_shufflevector(rx[n][0], rx[n][1], 0,1,2,3, 8,9,10,11);   \
        s16x8 bxl = __builtin_shufflevector(rx[n][0], rx[n][1], 4,5,6,7, 12,13,14,15); \
        s16x8 byh = __builtin_shufflevector(ry[n][0], ry[n][1], 0,1,2,3, 8,9,10,11);   \
        s16x8 byl = __builtin_shufflevector(ry[n][0], ry[n][1], 4,5,6,7, 12,13,14,15); \
        _Pragma("unroll")                                                         \
        for (int m = 0; m < 2; ++m) {                                             \
            accn[m][n] = MFMA(rAh[AB][m], bxh, accn[m][n], 0, 0, 0);              \
            accn[m][n] = MFMA(rAh[AB][m], bxl, accn[m][n], 0, 0, 0);              \
            accn[m][n] = MFMA(rAl[AB][m], bxh, accn[m][n], 0, 0, 0);              \
            accd[m][n] = MFMA(rAh[AB][m], byh, accd[m][n], 0, 0, 0);              \
            accd[m][n] = MFMA(rAh[AB][m], byl, accd[m][n], 0, 0, 0);              \
            accd[m][n] = MFMA(rAl[AB][m], byh, accd[m][n], 0, 0, 0);              \
        } } } while (0)

    // prologue: stage ALL 8 chunks (8 VMEM), then A0 (4 VMEM)
    STAGE(0); STAGE(1); STAGE(2); STAGE(3);
    STAGE(4); STAGE(5); STAGE(6); STAGE(7);
    __builtin_amdgcn_sched_barrier(0);
    LOADA(0, 0);
    __builtin_amdgcn_sched_barrier(0);

    // wait: own S0..S3 retired (12 issued, <=8 outstanding -> >=4 retired)
    asm volatile("s_waitcnt vmcnt(8)" ::: "memory");
    __builtin_amdgcn_s_barrier();
    __builtin_amdgcn_sched_barrier(0);

    LOADA(1, 1); LOADB(0); COMPUTE(0);
    LOADA(0, 2); LOADB(1); COMPUTE(1);
    LOADA(1, 3); LOADB(2); COMPUTE(0);
    LOADA(0, 4); LOADB(3); COMPUTE(1);

    // wait: own S0..S7 retired (28 issued by now, <=20 outstanding -> >=8 retired)
    asm volatile("s_waitcnt vmcnt(20)" ::: "memory");
    __builtin_amdgcn_s_barrier();
    __builtin_amdgcn_sched_barrier(0);

    LOADA(1, 5); LOADB(4); COMPUTE(0);
    LOADA(0, 6); LOADB(5); COMPUTE(1);
    LOADA(1, 7); LOADB(6); COMPUTE(0);
    LOADB(7); COMPUTE(1);

#undef COMPUTE
#undef LOADB
#undef LOADA
#undef STAGE
#undef MFMA

    float inv_scw = 1.f / (sums[1] + EPSV);
    #pragma unroll
    for (int m = 0; m < 2; ++m)
        #pragma unroll
        for (int n = 0; n < 2; ++n)
            #pragma unroll
            for (int r = 0; r < 4; ++r) {
                int o   = o0 + m * 16 + l4 * 4 + r;
                int pix = pb * 32 + n * 16 + l15;
                size_t oidx = ((size_t)(b * C4 + o)) * NPIX + pix;
                float nv = accn[m][n][r], dv = accd[m][n][r];
                out[oidx]      = nv / (dv + EPSV);
                out[NT + oidx] = dv * inv_scw;
            }
}

} // namespace

extern "C" void kernel_launch(void* const* d_in, const int* in_sizes, int n_in,
                              void* d_out, int out_size, void* d_ws, size_t ws_size,
                              hipStream_t stream) {
    const float* d    = (const float*)d_in[0];
    const float* cd   = (const float*)d_in[1];
    const float* s    = (const float*)d_in[2];
    const float* cs   = (const float*)d_in[3];
    const float* w_s  = (const float*)d_in[4];
    const float* wprp = (const float*)d_in[5];
    const float* cw   = (const float*)d_in[6];
    const float* sw   = (const float*)d_in[7];
    float* out = (float*)d_out;

    ushort_t* XP  = (ushort_t*)d_ws;
    ushort_t* YP  = XP + 2 * NT;
    ushort_t* cwH = YP + 2 * NT;
    ushort_t* cwL = cwH + C4 * C4;
    float* sums   = (float*)(cwL + C4 * C4);

    k_sums<<<1, 256, 0, stream>>>(sw, cw, sums);
    k_prep<<<C4, 256, 0, stream>>>(cw, cwH, cwL);
    k_stage12<<<dim3(B_ * C_ * (H_ / TILE) * (W_ / TILE)), 256, 0, stream>>>(
        d, cd, s, cs, w_s, wprp, sw, sums, XP, YP);
    k_stage3<<<dim3(PB, B_), 512, 0, stream>>>(XP, YP, cwH, cwL, sums, out);
}